// Round 1
// baseline (551.891 us; speedup 1.0000x reference)
//
#include <hip/hip_runtime.h>
#include <math.h>

#define HW_IMG (1u<<20)   // 1024*1024
#define W_ 1024
#define H_ 1024
#define B_ 4
#define C_ 8
#define N_LR 65536        // 256*256

__device__ __forceinline__ int refl1024(int i){
  if(i<0) i=-i;
  if(i>1023) i=2046-i;
  return i;
}

// ---------------- K1: downsample pan + accumulate normal equations ----------
__global__ __launch_bounds__(256) void k_fit(const float* __restrict__ lr_ms,
                                             const float* __restrict__ hr_pan,
                                             double* __restrict__ atab){
  int b = blockIdx.y;
  int tid = blockIdx.x*256 + threadIdx.x;       // 0..16383, each does 4 pixels
  double acc[54];
  #pragma unroll
  for(int i=0;i<54;i++) acc[i]=0.0;
  const float* pan = hr_pan + (size_t)b*HW_IMG;
  const float* lr  = lr_ms + (size_t)b*C_*N_LR;
  for(int k=0;k<4;k++){
    int n = tid*4+k;
    int i = n>>8, j = n&255;
    float s=0.f;
    #pragma unroll
    for(int dy=0;dy<4;dy++){
      const float* pr = pan + (size_t)(i*4+dy)*W_ + j*4;
      s += pr[0]+pr[1]+pr[2]+pr[3];
    }
    float bv = s*(1.f/16.f);
    float a[9];
    a[0]=1.f;
    #pragma unroll
    for(int c=0;c<C_;c++) a[c+1]=lr[(size_t)c*N_LR + n];
    int idx=0;
    #pragma unroll
    for(int p=0;p<9;p++){
      #pragma unroll
      for(int q=p;q<9;q++){ acc[idx] += (double)a[p]*(double)a[q]; idx++; }
    }
    #pragma unroll
    for(int p=0;p<9;p++) acc[45+p] += (double)a[p]*(double)bv;
  }
  #pragma unroll
  for(int v=0;v<54;v++){
    double x = acc[v];
    for(int off=32;off>0;off>>=1) x += __shfl_down(x, off, 64);
    if((threadIdx.x & 63)==0) atomicAdd(&atab[b*54+v], x);
  }
}

// ---------------- K2: 9x9 solve per batch (f64, partial pivot) -------------
__global__ void k_solve(const double* __restrict__ atab, double* __restrict__ sol){
  int b = threadIdx.x;
  if(b>=B_) return;
  double A[9][10];
  const double* src = atab + b*54;
  int idx=0;
  for(int p=0;p<9;p++)
    for(int q=p;q<9;q++){ A[p][q]=src[idx]; A[q][p]=src[idx]; idx++; }
  for(int p=0;p<9;p++) A[p][9]=src[45+p];
  for(int col=0; col<9; col++){
    int piv=col; double mx=fabs(A[col][col]);
    for(int r=col+1;r<9;r++){ double v=fabs(A[r][col]); if(v>mx){mx=v;piv=r;} }
    if(piv!=col){
      for(int c2=col;c2<10;c2++){ double t=A[col][c2]; A[col][c2]=A[piv][c2]; A[piv][c2]=t; }
    }
    double inv = 1.0/A[col][col];
    for(int r=col+1;r<9;r++){
      double f = A[r][col]*inv;
      for(int c2=col;c2<10;c2++) A[r][c2] -= f*A[col][c2];
    }
  }
  double x[9];
  for(int r=8;r>=0;r--){
    double s=A[r][9];
    for(int c2=r+1;c2<9;c2++) s -= A[r][c2]*x[c2];
    x[r]=s/A[r][r];
  }
  for(int i=0;i<9;i++) sol[b*9+i]=x[i];
}

// ---------------- K3: synthesize M_, G_, and D = sum_c |fuse-hr| -----------
__global__ __launch_bounds__(256) void k_synth(const float* __restrict__ hr_ms,
                                               const float* __restrict__ fuse_ms,
                                               const double* __restrict__ sol,
                                               float* __restrict__ M,
                                               float* __restrict__ G,
                                               float* __restrict__ D){
  size_t p = (size_t)blockIdx.x*256 + threadIdx.x;   // < 4*2^20
  int b = (int)(p >> 20);
  size_t pix = p & (size_t)(HW_IMG-1);
  const double* s = sol + b*9;
  float bias = (float)s[0];
  float m = bias, g = bias, d = 0.f;
  #pragma unroll
  for(int c=0;c<C_;c++){
    float w = (float)s[c+1];
    size_t off = (((size_t)b*C_ + c)<<20) + pix;
    float hv = hr_ms[off];
    float fv = fuse_ms[off];
    m = fmaf(w, hv, m);
    g = fmaf(w, fv, g);
    d += fabsf(fv-hv);
  }
  M[p]=m; G[p]=g; D[p]=d;
}

// ---------------- K4: vertical box blur (running sums per column) ----------
__global__ __launch_bounds__(256) void k_vblur(const float* __restrict__ M,
                                               const float* __restrict__ P,
                                               const float* __restrict__ G,
                                               float* __restrict__ VB){
  int x  = blockIdx.x*256 + threadIdx.x;  // 0..1023
  int b  = blockIdx.y;
  int y0 = blockIdx.z * 16;               // 64 segments of 16 rows
  const float* Mp = M + (size_t)b*HW_IMG;
  const float* Pp = P + (size_t)b*HW_IMG;
  const float* Gp = G + (size_t)b*HW_IMG;
  float S0=0,S1=0,S2=0,S3=0,S4=0,S5=0,S6=0;
  #define TAPV(yy, op) { int r = refl1024(yy); size_t off=(size_t)r*W_+x; \
    float mv=Mp[off], pv=Pp[off], gv=Gp[off]; \
    S0 op mv; S1 op pv; S2 op mv*pv; S3 op mv*mv; S4 op pv*pv; S5 op gv; S6 op gv*gv; }
  for(int k=y0-15;k<=y0+15;k++) TAPV(k, +=);
  const float inv = 1.f/31.f;
  size_t base = (size_t)b*HW_IMG + (size_t)y0*W_ + x;
  const size_t CH = (size_t)B_*HW_IMG;
  for(int i=0;i<16;i++){
    size_t o = base + (size_t)i*W_;
    VB[o]      = S0*inv; VB[CH+o]   = S1*inv; VB[2*CH+o] = S2*inv;
    VB[3*CH+o] = S3*inv; VB[4*CH+o] = S4*inv; VB[5*CH+o] = S5*inv;
    VB[6*CH+o] = S6*inv;
    if(i<15){
      int y = y0+i;
      TAPV(y+16, +=);
      TAPV(y-15, -=);
    }
  }
  #undef TAPV
}

// ---------------- K5: horizontal blur + loss terms -------------------------
#define LIDX(i) ((i)+((i)>>5))
__global__ __launch_bounds__(64) void k_hfinal(const float* __restrict__ VB,
                                               const float* __restrict__ P,
                                               const float* __restrict__ G,
                                               const float* __restrict__ D,
                                               double* __restrict__ acc){
  __shared__ float lds[7*1056];
  int row = blockIdx.x;           // 0..4095
  int b = row>>10, y = row&1023;
  int t = threadIdx.x;            // 0..63
  size_t rowoff = (size_t)b*HW_IMG + (size_t)y*W_;
  const size_t CH = (size_t)B_*HW_IMG;
  for(int ch=0; ch<7; ch++){
    const float* src = VB + (size_t)ch*CH + rowoff;
    float* dst = lds + ch*1056;
    for(int i=t*4; i<1024; i+=256){
      float4 v = *(const float4*)(src+i);
      dst[LIDX(i)]   = v.x;
      dst[LIDX(i+1)] = v.y;
      dst[LIDX(i+2)] = v.z;
      dst[LIDX(i+3)] = v.w;
    }
  }
  int x0 = t*16;
  float pv[16], gv[16], dv[16];
  {
    const float* Pr = P + rowoff + x0;
    const float* Gr = G + rowoff + x0;
    const float* Dr = D + rowoff + x0;
    #pragma unroll
    for(int i=0;i<4;i++){
      float4 a = *(const float4*)(Pr + i*4);
      pv[i*4]=a.x; pv[i*4+1]=a.y; pv[i*4+2]=a.z; pv[i*4+3]=a.w;
      float4 c = *(const float4*)(Gr + i*4);
      gv[i*4]=c.x; gv[i*4+1]=c.y; gv[i*4+2]=c.z; gv[i*4+3]=c.w;
      float4 e = *(const float4*)(Dr + i*4);
      dv[i*4]=e.x; dv[i*4+1]=e.y; dv[i*4+2]=e.z; dv[i*4+3]=e.w;
    }
  }
  __syncthreads();
  float S[7];
  #pragma unroll
  for(int ch=0;ch<7;ch++) S[ch]=0.f;
  #define TAPH(xx, op) { int r=refl1024(xx); int li=LIDX(r); \
    S[0] op lds[li];        S[1] op lds[1056+li];   S[2] op lds[2*1056+li]; \
    S[3] op lds[3*1056+li]; S[4] op lds[4*1056+li]; S[5] op lds[5*1056+li]; \
    S[6] op lds[6*1056+li]; }
  for(int k=x0-15;k<=x0+15;k++) TAPH(k, +=);
  const float inv = 1.f/31.f;
  float lc=0.f, la=0.f;
  #pragma unroll
  for(int i=0;i<16;i++){
    float mM=S[0]*inv, mP=S[1]*inv, mMP=S[2]*inv, mMM=S[3]*inv,
          mPP=S[4]*inv, mG=S[5]*inv, mGG=S[6]*inv;
    float cov  = mMP - mM*mP;
    float stdM = sqrtf(fabsf(mMM - mM*mM)+1e-10f);
    float stdP = sqrtf(fabsf(mPP - mP*mP)+1e-10f);
    float stdG = sqrtf(fabsf(mGG - mG*mG)+1e-10f);
    float corr = cov/(stdM*stdP);
    float c2 = corr*corr;
    float S4v = c2*c2;                       // S = corr^4 >= 0
    float gradP = (pv[i]-mP)/stdP;
    float gradG = (gv[i]-mG)/stdG;
    lc += dv[i]*S4v;                         // sum_c |fuse-hr| * S
    la += fabsf((gradG-gradP)*(2.f-S4v));
    if(i<15){
      int x = x0+i;
      TAPH(x+16, +=);
      TAPH(x-15, -=);
    }
  }
  #undef TAPH
  for(int off=32;off>0;off>>=1){
    lc += __shfl_down(lc, off, 64);
    la += __shfl_down(la, off, 64);
  }
  if(t==0){
    atomicAdd(&acc[0], (double)lc);
    atomicAdd(&acc[1], (double)la);
  }
}

// ---------------- K6: final scalar --------------------------------------
__global__ void k_out(const double* __restrict__ acc, float* __restrict__ out){
  out[0] = (float)(acc[0]*(1.0/33554432.0) + acc[1]*(1.0/4194304.0));
}

extern "C" void kernel_launch(void* const* d_in, const int* in_sizes, int n_in,
                              void* d_out, int out_size, void* d_ws, size_t ws_size,
                              hipStream_t stream){
  const float* lr_ms   = (const float*)d_in[0];
  const float* hr_pan  = (const float*)d_in[1];
  const float* hr_ms   = (const float*)d_in[2];
  const float* fuse_ms = (const float*)d_in[3];
  float* out = (float*)d_out;

  char* ws = (char*)d_ws;
  double* atab = (double*)ws;                 // 4*54 doubles
  double* sol  = (double*)(ws + 4096);        // 36 doubles
  double* acc  = (double*)(ws + 8192);        // 2 doubles
  float* M  = (float*)(ws + 16384);
  float* G  = M + (size_t)B_*HW_IMG;
  float* Dd = G + (size_t)B_*HW_IMG;
  float* VB = Dd + (size_t)B_*HW_IMG;         // 7 channels of B*H*W

  hipMemsetAsync(d_ws, 0, 16384, stream);     // zero atab + acc
  k_fit  <<<dim3(64,4),   256, 0, stream>>>(lr_ms, hr_pan, atab);
  k_solve<<<1,            64,  0, stream>>>(atab, sol);
  k_synth<<<16384,        256, 0, stream>>>(hr_ms, fuse_ms, sol, M, G, Dd);
  k_vblur<<<dim3(4,4,64), 256, 0, stream>>>(M, hr_pan, G, VB);
  k_hfinal<<<4096,        64,  0, stream>>>(VB, hr_pan, G, Dd, acc);
  k_out  <<<1, 1, 0, stream>>>(acc, out);
}

// Round 2
// 460.332 us; speedup vs baseline: 1.1989x; 1.1989x over previous
//
#include <hip/hip_runtime.h>
#include <math.h>

#define HW_IMG (1u<<20)   // 1024*1024
#define W_ 1024
#define H_ 1024
#define B_ 4
#define C_ 8
#define N_LR 65536        // 256*256

__device__ __forceinline__ int refl1024(int i){
  if(i<0) i=-i;
  if(i>1023) i=2046-i;
  return i;
}

// ---------------- K1: downsample pan + accumulate normal equations ----------
// f32 per-thread accumulation (4 px, rel err ~2e-7), f64 only at the atomic.
__global__ __launch_bounds__(256) void k_fit(const float* __restrict__ lr_ms,
                                             const float* __restrict__ hr_pan,
                                             double* __restrict__ atab){
  int b = blockIdx.y;
  int tid = blockIdx.x*256 + threadIdx.x;       // 0..16383, each does 4 pixels
  float acc[54];
  #pragma unroll
  for(int i=0;i<54;i++) acc[i]=0.f;
  const float* pan = hr_pan + (size_t)b*HW_IMG;
  const float* lr  = lr_ms + (size_t)b*C_*N_LR;
  for(int k=0;k<4;k++){
    int n = tid*4+k;
    int i = n>>8, j = n&255;
    float s=0.f;
    #pragma unroll
    for(int dy=0;dy<4;dy++){
      const float* pr = pan + (size_t)(i*4+dy)*W_ + j*4;
      s += pr[0]+pr[1]+pr[2]+pr[3];
    }
    float bv = s*(1.f/16.f);
    float a[9];
    a[0]=1.f;
    #pragma unroll
    for(int c=0;c<C_;c++) a[c+1]=lr[(size_t)c*N_LR + n];
    int idx=0;
    #pragma unroll
    for(int p=0;p<9;p++){
      #pragma unroll
      for(int q=p;q<9;q++){ acc[idx] = fmaf(a[p],a[q],acc[idx]); idx++; }
    }
    #pragma unroll
    for(int p=0;p<9;p++) acc[45+p] = fmaf(a[p],bv,acc[45+p]);
  }
  #pragma unroll
  for(int v=0;v<54;v++){
    float x = acc[v];
    for(int off=32;off>0;off>>=1) x += __shfl_down(x, off, 64);
    if((threadIdx.x & 63)==0) atomicAdd(&atab[b*54+v], (double)x);
  }
}

// ---------------- K2: 9x9 solve per batch (f64, partial pivot) -------------
__global__ void k_solve(const double* __restrict__ atab, double* __restrict__ sol){
  int b = threadIdx.x;
  if(b>=B_) return;
  double A[9][10];
  const double* src = atab + b*54;
  int idx=0;
  for(int p=0;p<9;p++)
    for(int q=p;q<9;q++){ A[p][q]=src[idx]; A[q][p]=src[idx]; idx++; }
  for(int p=0;p<9;p++) A[p][9]=src[45+p];
  for(int col=0; col<9; col++){
    int piv=col; double mx=fabs(A[col][col]);
    for(int r=col+1;r<9;r++){ double v=fabs(A[r][col]); if(v>mx){mx=v;piv=r;} }
    if(piv!=col){
      for(int c2=col;c2<10;c2++){ double t=A[col][c2]; A[col][c2]=A[piv][c2]; A[piv][c2]=t; }
    }
    double inv = 1.0/A[col][col];
    for(int r=col+1;r<9;r++){
      double f = A[r][col]*inv;
      for(int c2=col;c2<10;c2++) A[r][c2] -= f*A[col][c2];
    }
  }
  double x[9];
  for(int r=8;r>=0;r--){
    double s=A[r][9];
    for(int c2=r+1;c2<9;c2++) s -= A[r][c2]*x[c2];
    x[r]=s/A[r][r];
  }
  for(int i=0;i<9;i++) sol[b*9+i]=x[i];
}

// ---------------- K3: synthesize M_, G_, D = sum_c |fuse-hr| (float4) ------
__global__ __launch_bounds__(256) void k_synth(const float* __restrict__ hr_ms,
                                               const float* __restrict__ fuse_ms,
                                               const double* __restrict__ sol,
                                               float* __restrict__ M,
                                               float* __restrict__ G,
                                               float* __restrict__ D){
  size_t t = (size_t)blockIdx.x*256 + threadIdx.x;   // < 2^20, 4 px each
  int b = (int)(t >> 18);
  size_t pix = (t & (size_t)((1<<18)-1))*4;
  const double* s = sol + b*9;
  float bias = (float)s[0];
  float4 m = {bias,bias,bias,bias};
  float4 g = m;
  float4 d = {0.f,0.f,0.f,0.f};
  #pragma unroll
  for(int c=0;c<C_;c++){
    float w = (float)s[c+1];
    size_t off = (((size_t)b*C_ + c)<<20) + pix;
    float4 hv = *(const float4*)(hr_ms+off);
    float4 fv = *(const float4*)(fuse_ms+off);
    m.x=fmaf(w,hv.x,m.x); m.y=fmaf(w,hv.y,m.y); m.z=fmaf(w,hv.z,m.z); m.w=fmaf(w,hv.w,m.w);
    g.x=fmaf(w,fv.x,g.x); g.y=fmaf(w,fv.y,g.y); g.z=fmaf(w,fv.z,g.z); g.w=fmaf(w,fv.w,g.w);
    d.x+=fabsf(fv.x-hv.x); d.y+=fabsf(fv.y-hv.y); d.z+=fabsf(fv.z-hv.z); d.w+=fabsf(fv.w-hv.w);
  }
  size_t p = ((size_t)b<<20) + pix;
  *(float4*)(M+p)=m; *(float4*)(G+p)=g; *(float4*)(D+p)=d;
}

// ---------------- K4: vertical box blur (running sums per column) ----------
__global__ __launch_bounds__(256) void k_vblur(const float* __restrict__ M,
                                               const float* __restrict__ P,
                                               const float* __restrict__ G,
                                               float* __restrict__ VB){
  int x  = blockIdx.x*256 + threadIdx.x;  // 0..1023
  int b  = blockIdx.y;
  int y0 = blockIdx.z * 16;               // 64 segments of 16 rows
  const float* Mp = M + (size_t)b*HW_IMG;
  const float* Pp = P + (size_t)b*HW_IMG;
  const float* Gp = G + (size_t)b*HW_IMG;
  float S0=0,S1=0,S2=0,S3=0,S4=0,S5=0,S6=0;
  #define TAPV(yy, op) { int r = refl1024(yy); size_t off=(size_t)r*W_+x; \
    float mv=Mp[off], pv=Pp[off], gv=Gp[off]; \
    S0 op mv; S1 op pv; S2 op mv*pv; S3 op mv*mv; S4 op pv*pv; S5 op gv; S6 op gv*gv; }
  for(int k=y0-15;k<=y0+15;k++) TAPV(k, +=);
  const float inv = 1.f/31.f;
  size_t base = (size_t)b*HW_IMG + (size_t)y0*W_ + x;
  const size_t CH = (size_t)B_*HW_IMG;
  for(int i=0;i<16;i++){
    size_t o = base + (size_t)i*W_;
    VB[o]      = S0*inv; VB[CH+o]   = S1*inv; VB[2*CH+o] = S2*inv;
    VB[3*CH+o] = S3*inv; VB[4*CH+o] = S4*inv; VB[5*CH+o] = S5*inv;
    VB[6*CH+o] = S6*inv;
    if(i<15){
      int y = y0+i;
      TAPV(y+16, +=);
      TAPV(y-15, -=);
    }
  }
  #undef TAPV
}

// ---------------- K5: horizontal blur + loss terms -------------------------
// 128 threads/block, one row per block, 8 px/thread. LDS 29.6 KB -> 5 blk/CU
// x 2 waves = 10 waves/CU (was 5). Per-block partials instead of global
// atomics (removes same-address f64 atomic serialization).
#define LIDX(i) ((i)+((i)>>5))
__global__ __launch_bounds__(128) void k_hfinal(const float* __restrict__ VB,
                                                const float* __restrict__ P,
                                                const float* __restrict__ G,
                                                const float* __restrict__ D,
                                                double* __restrict__ partial){
  __shared__ float lds[7*1056];
  __shared__ float red[4];
  int row = blockIdx.x;           // 0..4095
  int b = row>>10, y = row&1023;
  int t = threadIdx.x;            // 0..127
  size_t rowoff = (size_t)b*HW_IMG + (size_t)y*W_;
  const size_t CH = (size_t)B_*HW_IMG;
  for(int ch=0; ch<7; ch++){
    const float* src = VB + (size_t)ch*CH + rowoff;
    float* dst = lds + ch*1056;
    for(int i=t*4; i<1024; i+=512){
      float4 v = *(const float4*)(src+i);
      dst[LIDX(i)]   = v.x;
      dst[LIDX(i+1)] = v.y;
      dst[LIDX(i+2)] = v.z;
      dst[LIDX(i+3)] = v.w;
    }
  }
  int x0 = t*8;
  float pv[8], gv[8], dv[8];
  {
    const float* Pr = P + rowoff + x0;
    const float* Gr = G + rowoff + x0;
    const float* Dr = D + rowoff + x0;
    #pragma unroll
    for(int i=0;i<2;i++){
      float4 a = *(const float4*)(Pr + i*4);
      pv[i*4]=a.x; pv[i*4+1]=a.y; pv[i*4+2]=a.z; pv[i*4+3]=a.w;
      float4 c = *(const float4*)(Gr + i*4);
      gv[i*4]=c.x; gv[i*4+1]=c.y; gv[i*4+2]=c.z; gv[i*4+3]=c.w;
      float4 e = *(const float4*)(Dr + i*4);
      dv[i*4]=e.x; dv[i*4+1]=e.y; dv[i*4+2]=e.z; dv[i*4+3]=e.w;
    }
  }
  __syncthreads();
  float S[7];
  #pragma unroll
  for(int ch=0;ch<7;ch++) S[ch]=0.f;
  #define TAPH(xx, op) { int r=refl1024(xx); int li=LIDX(r); \
    S[0] op lds[li];        S[1] op lds[1056+li];   S[2] op lds[2*1056+li]; \
    S[3] op lds[3*1056+li]; S[4] op lds[4*1056+li]; S[5] op lds[5*1056+li]; \
    S[6] op lds[6*1056+li]; }
  for(int k=x0-15;k<=x0+15;k++) TAPH(k, +=);
  const float inv = 1.f/31.f;
  float lc=0.f, la=0.f;
  #pragma unroll
  for(int i=0;i<8;i++){
    float mM=S[0]*inv, mP=S[1]*inv, mMP=S[2]*inv, mMM=S[3]*inv,
          mPP=S[4]*inv, mG=S[5]*inv, mGG=S[6]*inv;
    float cov  = mMP - mM*mP;
    float stdM = sqrtf(fabsf(mMM - mM*mM)+1e-10f);
    float stdP = sqrtf(fabsf(mPP - mP*mP)+1e-10f);
    float stdG = sqrtf(fabsf(mGG - mG*mG)+1e-10f);
    float corr = cov/(stdM*stdP);
    float c2 = corr*corr;
    float S4v = c2*c2;                       // S = corr^4 >= 0
    float gradP = (pv[i]-mP)/stdP;
    float gradG = (gv[i]-mG)/stdG;
    lc += dv[i]*S4v;                         // sum_c |fuse-hr| * S
    la += fabsf((gradG-gradP)*(2.f-S4v));
    if(i<7){
      int x = x0+i;
      TAPH(x+16, +=);
      TAPH(x-15, -=);
    }
  }
  #undef TAPH
  for(int off=32;off>0;off>>=1){
    lc += __shfl_down(lc, off, 64);
    la += __shfl_down(la, off, 64);
  }
  int wid = t>>6;                 // 0..1
  if((t&63)==0){ red[wid*2]=lc; red[wid*2+1]=la; }
  __syncthreads();
  if(t==0){
    partial[(size_t)row*2]   = (double)red[0]+(double)red[2];
    partial[(size_t)row*2+1] = (double)red[1]+(double)red[3];
  }
}

// ---------------- K6: reduce partials + final scalar -----------------------
__global__ __launch_bounds__(256) void k_out(const double* __restrict__ partial,
                                             float* __restrict__ out){
  int t = threadIdx.x;
  double lc=0.0, la=0.0;
  for(int i=t;i<4096;i+=256){ lc+=partial[2*i]; la+=partial[2*i+1]; }
  for(int off=32;off>0;off>>=1){
    lc += __shfl_down(lc, off, 64);
    la += __shfl_down(la, off, 64);
  }
  __shared__ double red[8];
  int wid = t>>6;
  if((t&63)==0){ red[wid*2]=lc; red[wid*2+1]=la; }
  __syncthreads();
  if(t==0){
    double c = red[0]+red[2]+red[4]+red[6];
    double a = red[1]+red[3]+red[5]+red[7];
    out[0] = (float)(c*(1.0/33554432.0) + a*(1.0/4194304.0));
  }
}

extern "C" void kernel_launch(void* const* d_in, const int* in_sizes, int n_in,
                              void* d_out, int out_size, void* d_ws, size_t ws_size,
                              hipStream_t stream){
  const float* lr_ms   = (const float*)d_in[0];
  const float* hr_pan  = (const float*)d_in[1];
  const float* hr_ms   = (const float*)d_in[2];
  const float* fuse_ms = (const float*)d_in[3];
  float* out = (float*)d_out;

  char* ws = (char*)d_ws;
  double* atab    = (double*)ws;              // 4*54 doubles
  double* sol     = (double*)(ws + 4096);     // 36 doubles
  double* partial = (double*)(ws + 8192);     // 4096*2 doubles = 64 KB
  float* M  = (float*)(ws + 131072);
  float* G  = M + (size_t)B_*HW_IMG;
  float* Dd = G + (size_t)B_*HW_IMG;
  float* VB = Dd + (size_t)B_*HW_IMG;         // 7 channels of B*H*W

  hipMemsetAsync(d_ws, 0, 4096, stream);      // zero atab
  k_fit  <<<dim3(64,4),   256, 0, stream>>>(lr_ms, hr_pan, atab);
  k_solve<<<1,            64,  0, stream>>>(atab, sol);
  k_synth<<<4096,         256, 0, stream>>>(hr_ms, fuse_ms, sol, M, G, Dd);
  k_vblur<<<dim3(4,4,64), 256, 0, stream>>>(M, hr_pan, G, VB);
  k_hfinal<<<4096,        128, 0, stream>>>(VB, hr_pan, G, Dd, partial);
  k_out  <<<1, 256, 0, stream>>>(partial, out);
}